// Round 3
// baseline (137.329 us; speedup 1.0000x reference)
//
#include <hip/hip_runtime.h>

#define T_SEQ 2048
#define C_DIM 1024
#define NH    16
#define NKV   4
#define HD    64
#define WIN   512

typedef __bf16 bf16x8 __attribute__((ext_vector_type(8)));
typedef __bf16 bf16x4 __attribute__((ext_vector_type(4)));
typedef float f32x4 __attribute__((ext_vector_type(4)));

#define MFMA16(a, b, c) __builtin_amdgcn_mfma_f32_16x16x32_bf16(a, b, c, 0, 0, 0)

// async global->LDS, 16B per lane, dest = wave-uniform base + lane*16
#define GLD16(g, s)                                                          \
  __builtin_amdgcn_global_load_lds(                                          \
      (const __attribute__((address_space(1))) void*)(g),                    \
      (__attribute__((address_space(3))) void*)(s), 16, 0, 0)

// ---------------- prep: fused f32->bf16 casts + RoPE table (R7, proven) ----------------
__global__ __launch_bounds__(256) void prep_kernel(const float* __restrict__ x,
                                                   const float* __restrict__ Wq,
                                                   const float* __restrict__ Wkv,
                                                   const float* __restrict__ Wp,
                                                   __bf16* __restrict__ xb,
                                                   __bf16* __restrict__ Wqkvb,
                                                   __bf16* __restrict__ Wpb,
                                                   float2* __restrict__ ropeT) {
  int b = blockIdx.x;
  if (b >= 4608) {
    int idx = (b - 4608) * 256 + threadIdx.x;  // < 65536
    int t = idx >> 5, i = idx & 31;
    float theta = exp2f(-(float)i * (13.287712379549449f / 32.0f));
    float s, c;
    sincosf((float)t * theta, &s, &c);
    ropeT[idx] = make_float2(c, s);
    return;
  }
  const float* src;
  __bf16* dst;
  int off;
  if (b < 2048)      { src = x;   dst = xb;                off = b; }
  else if (b < 3072) { src = Wq;  dst = Wqkvb;             off = b - 2048; }
  else if (b < 3584) { src = Wkv; dst = Wqkvb + (1 << 20); off = b - 3072; }
  else               { src = Wp;  dst = Wpb;               off = b - 3584; }
  int i = off * 1024 + threadIdx.x * 4;
  float4 v = *(const float4*)(src + i);
  bf16x4 o;
  o[0] = (__bf16)v.x; o[1] = (__bf16)v.y; o[2] = (__bf16)v.z; o[3] = (__bf16)v.w;
  *(bf16x4*)(dst + i) = o;
}

// ---------------- GEMM core: 64x64 tile, BK=64, global_load_lds staging + LDS dbuf ----
// R1-proven form (127.6 us). R2's counted-vmcnt 3-buffer pipeline was null -> the
// GEMMs are not drain-bound; keep the simpler 2-buffer core.
// global_load_lds writes LDS linearly (wave base + lane*16B), so the XOR chunk
// swizzle moves to the GLOBAL source address (m173): LDS[row][c] = G[row][c^(row&7)].
// Waves stage 8-row groups: row&7 == l>>3, swizzled source chunk = (l&7)^(l>>3).
__device__ __forceinline__ void gemm_core64(const __bf16* __restrict__ A,
                                            const __bf16* __restrict__ B,
                                            int K,
                                            __bf16* AsB, __bf16* BsB,
                                            f32x4 (&acc)[4]) {
  const int tid = threadIdx.x;
  const int w = tid >> 6, l = tid & 63;
  const int quad = l >> 4, r16 = l & 15;
  const int srow = w * 16 + (l >> 3);
  const size_t soff = (size_t)srow * K + (size_t)(((l & 7) ^ (l >> 3)) * 8);
  const __bf16* gA = A + soff;
  const __bf16* gB = B + soff;
  __bf16* const lA = AsB + w * 1024;
  __bf16* const lB = BsB + w * 1024;
  const size_t rstep = (size_t)8 * K;
  int rA[2], rB[4][2];
#pragma unroll
  for (int ks = 0; ks < 2; ++ks) {
    int row = w * 16 + r16;
    rA[ks] = row * 64 + (((ks * 4 + quad) ^ (row & 7)) * 8);
  }
#pragma unroll
  for (int nt = 0; nt < 4; ++nt)
#pragma unroll
    for (int ks = 0; ks < 2; ++ks) {
      int row = nt * 16 + r16;
      rB[nt][ks] = row * 64 + (((ks * 4 + quad) ^ (row & 7)) * 8);
    }
  const int nIter = K >> 6;
  GLD16(gA, lA);
  GLD16(gA + rstep, lA + 512);
  GLD16(gB, lB);
  GLD16(gB + rstep, lB + 512);
  __syncthreads();
  int cur = 0;
  for (int it = 0; it < nIter; ++it) {
    if (it + 1 < nIter) {  // async-stage next K-slab into the other buffer
      const __bf16* ga = gA + ((it + 1) << 6);
      const __bf16* gb = gB + ((it + 1) << 6);
      __bf16* la = lA + ((cur ^ 1) << 12);
      __bf16* lb = lB + ((cur ^ 1) << 12);
      GLD16(ga, la);
      GLD16(ga + rstep, la + 512);
      GLD16(gb, lb);
      GLD16(gb + rstep, lb + 512);
    }
    const __bf16* Asc = AsB + (cur << 12);
    const __bf16* Bsc = BsB + (cur << 12);
#pragma unroll
    for (int ks = 0; ks < 2; ++ks) {
      bf16x8 fa  = *(const bf16x8*)(Asc + rA[ks]);
      bf16x8 fb0 = *(const bf16x8*)(Bsc + rB[0][ks]);
      bf16x8 fb1 = *(const bf16x8*)(Bsc + rB[1][ks]);
      bf16x8 fb2 = *(const bf16x8*)(Bsc + rB[2][ks]);
      bf16x8 fb3 = *(const bf16x8*)(Bsc + rB[3][ks]);
      acc[0] = MFMA16(fa, fb0, acc[0]);
      acc[1] = MFMA16(fa, fb1, acc[1]);
      acc[2] = MFMA16(fa, fb2, acc[2]);
      acc[3] = MFMA16(fa, fb3, acc[3]);
    }
    if (it + 1 < nIter) {
      __syncthreads();  // drains vmcnt(0): next slab resident; old buffer free
      cur ^= 1;
    }
  }
}

// ---------------- QKV GEMM + fused norm+RoPE (Q,K) / V-transpose epilogue ----------
__global__ __launch_bounds__(256) void gemm_qkv_kernel(const __bf16* __restrict__ xb,
                                                       const __bf16* __restrict__ Wqkvb,
                                                       const float2* __restrict__ ropeT,
                                                       __bf16* __restrict__ Qb,
                                                       __bf16* __restrict__ Kb,
                                                       __bf16* __restrict__ Vt) {
  __shared__ __align__(16) __bf16 smem[16384];  // As 2x4096 | Bs 2x4096 (32 KB)
  __bf16* AsB = smem;
  __bf16* BsB = smem + 8192;
  f32x4 acc[4] = {};
  const int m0 = blockIdx.y * 64, n0 = blockIdx.x * 64;
  gemm_core64(xb + (size_t)m0 * C_DIM, Wqkvb + (size_t)n0 * C_DIM, C_DIM, AsB, BsB, acc);
  const int tid = threadIdx.x;
  const int w = tid >> 6, l = tid & 63, quad = l >> 4, r16 = l & 15;
  if (n0 < 1280) {  // Q or K: L2-norm + RoPE
    const bool isQ = n0 < 1024;
    const int head = isQ ? (n0 >> 6) : ((n0 - 1024) >> 6);
    __bf16* dstBase = (isQ ? Qb : Kb) + (size_t)head * T_SEQ * HD;
    const float osc = isQ ? 0.125f : 1.0f;  // fold 1/sqrt(d) into Q (2^-3 exact)
#pragma unroll
    for (int r = 0; r < 4; ++r) {
      float ss = acc[0][r] * acc[0][r] + acc[1][r] * acc[1][r] +
                 acc[2][r] * acc[2][r] + acc[3][r] * acc[3][r];
#pragma unroll
      for (int m = 1; m < 16; m <<= 1) ss += __shfl_xor(ss, m, 64);
      const float inv = osc / (sqrtf(ss) + 1e-6f);
      const int t = m0 + w * 16 + quad * 4 + r;
      const float2 cs0 = ropeT[t * 32 + r16];
      const float2 cs1 = ropeT[t * 32 + 16 + r16];
      const float v0 = acc[0][r] * inv, v1 = acc[1][r] * inv;
      const float v2 = acc[2][r] * inv, v3 = acc[3][r] * inv;
      __bf16* dst = dstBase + (size_t)t * HD;
      dst[r16]      = (__bf16)(v0 * cs0.x - v2 * cs0.y);
      dst[16 + r16] = (__bf16)(v1 * cs1.x - v3 * cs1.y);
      dst[32 + r16] = (__bf16)(v2 * cs0.x + v0 * cs0.y);
      dst[48 + r16] = (__bf16)(v3 * cs1.x + v1 * cs1.y);
    }
  } else {  // V: transpose to Vt[kvh][d][t] via reused LDS
    const int kvh = (n0 - 1280) >> 6;
    __syncthreads();  // all waves done reading As/Bs
    __bf16* Vs = smem;  // [64 d][stride 136] = 17.4 KB <= 32 KB
#pragma unroll
    for (int nt = 0; nt < 4; ++nt)
#pragma unroll
      for (int r = 0; r < 4; ++r)
        Vs[(nt * 16 + r16) * 136 + w * 16 + quad * 4 + r] = (__bf16)acc[nt][r];
    __syncthreads();
    const int d = tid >> 2, tc = (tid & 3) * 16;
    __bf16* dst = Vt + ((size_t)kvh * HD + d) * T_SEQ + m0 + tc;
    bf16x8 v0 = *(const bf16x8*)(Vs + d * 136 + tc);
    bf16x8 v1 = *(const bf16x8*)(Vs + d * 136 + tc + 8);
    *(bf16x8*)dst = v0;
    *(bf16x8*)(dst + 8) = v1;
  }
}

// ---------------- proj GEMM: grid (16, 32), f32 epilogue ----------------
__global__ __launch_bounds__(256) void gemm_proj_kernel(const __bf16* __restrict__ Yb,
                                                        const __bf16* __restrict__ Wpb,
                                                        float* __restrict__ C) {
  __shared__ __align__(16) __bf16 smem[16384];
  __bf16* AsB = smem;
  __bf16* BsB = smem + 8192;
  f32x4 acc[4] = {};
  const int m0 = blockIdx.y * 64, n0 = blockIdx.x * 64;
  gemm_core64(Yb + (size_t)m0 * C_DIM, Wpb + (size_t)n0 * C_DIM, C_DIM, AsB, BsB, acc);
  const int tid = threadIdx.x;
  const int w = tid >> 6, l = tid & 63, quad = l >> 4, r16 = l & 15;
  const int mrow = m0 + w * 16 + quad * 4;
  const int ncol = n0 + r16;
#pragma unroll
  for (int r = 0; r < 4; ++r) {
    size_t rowoff = (size_t)(mrow + r) * C_DIM;
    C[rowoff + ncol]      = acc[0][r];
    C[rowoff + ncol + 16] = acc[1][r];
    C[rowoff + ncol + 32] = acc[2][r];
    C[rowoff + ncol + 48] = acc[3][r];
  }
}

// ---------------- MFMA sliding-window attention, split-key blocks ----------
// R11: depth-1 register prefetch of the NEXT chunk's K fragments (T14 mechanism,
// m214v27 +17%): issue K(c+1) loads right after the current QK MFMAs so their
// ~300cyc L2 latency hides under exp/mask/P-roundtrip/PV (~400+ cyc). Named regs
// only (rule #20). Clamped next-index keeps the loads branch-free and in-bounds
// (chunk addresses stay < T_SEQ rows). Numerics identical to R7.
__global__ __launch_bounds__(256) void attn_mfma_kernel(const __bf16* __restrict__ Qb,
                                                        const __bf16* __restrict__ Kb,
                                                        const __bf16* __restrict__ Vt,
                                                        __bf16* __restrict__ Yb) {
  __shared__ __align__(16) __bf16 Pl[4][16][72];
  __shared__ __align__(16) float Oc[2][16][68];
  __shared__ float Ls[2][16];
  const int h = blockIdx.y, kvh = h >> 2;
  const int t0 = blockIdx.x * 32;
  const int tid = threadIdx.x;
  const int w = tid >> 6, l = tid & 63;
  const int quad = l >> 4, r16 = l & 15;
  const int sub = w & 1, half = w >> 1;
  const __bf16* qptr = Qb + ((size_t)h * T_SEQ + t0 + sub * 16 + r16) * HD + quad * 8;
  bf16x8 aq0 = *(const bf16x8*)(qptr);
  bf16x8 aq1 = *(const bf16x8*)(qptr + 32);
  const int keyStart = max(0, t0 - (WIN - 1)) & ~63;
  const int keyEnd = (t0 + 32 + 63) & ~63;
  const int nch = (keyEnd - keyStart) >> 6;   // <= 9
  const int nch2 = (nch + 1) >> 1;
  const int cbeg = half ? nch2 : 0;
  const int cend = half ? nch : nch2;
  const __bf16* kbase = Kb + (size_t)kvh * T_SEQ * HD;
  const __bf16* vbase = Vt + (size_t)kvh * HD * T_SEQ;
  const int tq_base = t0 + sub * 16 + quad * 4;
  f32x4 oacc[4] = {};
  float lsum[4] = {0.f, 0.f, 0.f, 0.f};
  // preload K fragments for first chunk (always-valid addresses even if loop empty)
  bf16x8 kA0, kA1, kB0, kB1, kC0, kC1, kD0, kD1;
  {
    const __bf16* kr = kbase + (size_t)(keyStart + (cbeg << 6) + r16) * HD + quad * 8;
    kA0 = *(const bf16x8*)kr;              kA1 = *(const bf16x8*)(kr + 32);
    kB0 = *(const bf16x8*)(kr + 16 * HD);  kB1 = *(const bf16x8*)(kr + 16 * HD + 32);
    kC0 = *(const bf16x8*)(kr + 32 * HD);  kC1 = *(const bf16x8*)(kr + 32 * HD + 32);
    kD0 = *(const bf16x8*)(kr + 48 * HD);  kD1 = *(const bf16x8*)(kr + 48 * HD + 32);
  }
  bf16x8 tA0, tA1, tB0, tB1, tC0, tC1, tD0, tD1;
  for (int c = cbeg; c < cend; ++c) {
    const int key0 = keyStart + (c << 6);
    f32x4 s[4] = {};
    s[0] = MFMA16(aq0, kA0, s[0]);  s[0] = MFMA16(aq1, kA1, s[0]);
    s[1] = MFMA16(aq0, kB0, s[1]);  s[1] = MFMA16(aq1, kB1, s[1]);
    s[2] = MFMA16(aq0, kC0, s[2]);  s[2] = MFMA16(aq1, kC1, s[2]);
    s[3] = MFMA16(aq0, kD0, s[3]);  s[3] = MFMA16(aq1, kD1, s[3]);
    {  // prefetch next chunk's K (clamped -> branch-free, always in-bounds)
      const int cn = (c + 1 < cend) ? (c + 1) : c;
      const __bf16* kr = kbase + (size_t)(keyStart + (cn << 6) + r16) * HD + quad * 8;
      tA0 = *(const bf16x8*)kr;              tA1 = *(const bf16x8*)(kr + 32);
      tB0 = *(const bf16x8*)(kr + 16 * HD);  tB1 = *(const bf16x8*)(kr + 16 * HD + 32);
      tC0 = *(const bf16x8*)(kr + 32 * HD);  tC1 = *(const bf16x8*)(kr + 32 * HD + 32);
      tD0 = *(const bf16x8*)(kr + 48 * HD);  tD1 = *(const bf16x8*)(kr + 48 * HD + 32);
    }
#pragma unroll
    for (int nt = 0; nt < 4; ++nt) {
      const int key = key0 + nt * 16 + r16;
#pragma unroll
      for (int r = 0; r < 4; ++r) {
        const int tq = tq_base + r;
        bool valid = (key <= tq) && (key > tq - WIN);
        float p = valid ? __expf(s[nt][r]) : 0.0f;
        lsum[r] += p;
        Pl[w][quad * 4 + r][nt * 16 + r16] = (__bf16)p;
      }
    }
    bf16x8 ap0 = *(const bf16x8*)(&Pl[w][r16][quad * 8]);
    bf16x8 ap1 = *(const bf16x8*)(&Pl[w][r16][32 + quad * 8]);
#pragma unroll
    for (int nt = 0; nt < 4; ++nt) {
      const __bf16* vr = vbase + (size_t)(nt * 16 + r16) * T_SEQ + key0 + quad * 8;
      bf16x8 bv0 = *(const bf16x8*)vr;
      bf16x8 bv1 = *(const bf16x8*)(vr + 32);
      oacc[nt] = MFMA16(ap0, bv0, oacc[nt]);
      oacc[nt] = MFMA16(ap1, bv1, oacc[nt]);
    }
    kA0 = tA0; kA1 = tA1; kB0 = tB0; kB1 = tB1;
    kC0 = tC0; kC1 = tC1; kD0 = tD0; kD1 = tD1;
  }
#pragma unroll
  for (int r = 0; r < 4; ++r) {
#pragma unroll
    for (int m = 1; m < 16; m <<= 1) lsum[r] += __shfl_xor(lsum[r], m, 64);
  }
  if (half == 1) {  // publish partials
#pragma unroll
    for (int nt = 0; nt < 4; ++nt)
#pragma unroll
      for (int r = 0; r < 4; ++r)
        Oc[sub][quad * 4 + r][nt * 16 + r16] = oacc[nt][r];
    if (r16 == 0) {
#pragma unroll
      for (int r = 0; r < 4; ++r) Ls[sub][quad * 4 + r] = lsum[r];
    }
  }
  __syncthreads();
  if (half == 0) {  // combine + normalize + store
#pragma unroll
    for (int r = 0; r < 4; ++r) {
      const float inv = 1.0f / (lsum[r] + Ls[sub][quad * 4 + r]);
      const size_t row = (size_t)(tq_base + r);
#pragma unroll
      for (int nt = 0; nt < 4; ++nt) {
        float o = oacc[nt][r] + Oc[sub][quad * 4 + r][nt * 16 + r16];
        Yb[row * C_DIM + h * HD + nt * 16 + r16] = (__bf16)(o * inv);
      }
    }
  }
}

extern "C" void kernel_launch(void* const* d_in, const int* in_sizes, int n_in,
                              void* d_out, int out_size, void* d_ws, size_t ws_size,
                              hipStream_t stream) {
  const float* x     = (const float*)d_in[0];
  const float* Wq    = (const float*)d_in[1];
  const float* Wkv   = (const float*)d_in[2];
  const float* Wproj = (const float*)d_in[3];
  float* out = (float*)d_out;

  __bf16* xb    = (__bf16*)d_ws;                         // [2048][1024]
  __bf16* Wqkvb = xb + (size_t)T_SEQ * C_DIM;            // [1536][1024]
  __bf16* Wpb   = Wqkvb + (size_t)1536 * C_DIM;          // [1024][1024]
  __bf16* Qb    = Wpb + (size_t)C_DIM * C_DIM;           // [16][2048][64]
  __bf16* Kb    = Qb + (size_t)NH * T_SEQ * HD;          // [4][2048][64]
  __bf16* Vt    = Kb + (size_t)NKV * T_SEQ * HD;         // [4][64][2048]
  __bf16* Yb    = Vt + (size_t)NKV * HD * T_SEQ;         // [2048][1024]
  float2* ropeT = (float2*)(Yb + (size_t)T_SEQ * C_DIM); // [2048][32]

  prep_kernel<<<4864, 256, 0, stream>>>(x, Wq, Wkv, Wproj, xb, Wqkvb, Wpb, ropeT);
  gemm_qkv_kernel<<<dim3(24, 32), 256, 0, stream>>>(xb, Wqkvb, ropeT, Qb, Kb, Vt);
  attn_mfma_kernel<<<dim3(T_SEQ / 32, NH), 256, 0, stream>>>(Qb, Kb, Vt, Yb);
  gemm_proj_kernel<<<dim3(16, 32), 256, 0, stream>>>(Yb, Wpb, out);
}

// Round 4
// 106.369 us; speedup vs baseline: 1.2911x; 1.2911x over previous
//
#include <hip/hip_runtime.h>

#define T_SEQ 2048
#define C_DIM 1024
#define NH    16
#define NKV   4
#define HD    64
#define WIN   512

typedef __bf16 bf16x8 __attribute__((ext_vector_type(8)));
typedef __bf16 bf16x4 __attribute__((ext_vector_type(4)));
typedef float f32x4 __attribute__((ext_vector_type(4)));

#define MFMA16(a, b, c) __builtin_amdgcn_mfma_f32_16x16x32_bf16(a, b, c, 0, 0, 0)

// async global->LDS, 16B per lane, dest = wave-uniform base + lane*16
#define GLD16(g, s)                                                          \
  __builtin_amdgcn_global_load_lds(                                          \
      (const __attribute__((address_space(1))) void*)(g),                    \
      (__attribute__((address_space(3))) void*)(s), 16, 0, 0)

// ---------------- prep: fused f32->bf16 casts + RoPE table (R7, proven) ----------------
__global__ __launch_bounds__(256) void prep_kernel(const float* __restrict__ x,
                                                   const float* __restrict__ Wq,
                                                   const float* __restrict__ Wkv,
                                                   const float* __restrict__ Wp,
                                                   __bf16* __restrict__ xb,
                                                   __bf16* __restrict__ Wqkvb,
                                                   __bf16* __restrict__ Wpb,
                                                   float2* __restrict__ ropeT) {
  int b = blockIdx.x;
  if (b >= 4608) {
    int idx = (b - 4608) * 256 + threadIdx.x;  // < 65536
    int t = idx >> 5, i = idx & 31;
    float theta = exp2f(-(float)i * (13.287712379549449f / 32.0f));
    float s, c;
    sincosf((float)t * theta, &s, &c);
    ropeT[idx] = make_float2(c, s);
    return;
  }
  const float* src;
  __bf16* dst;
  int off;
  if (b < 2048)      { src = x;   dst = xb;                off = b; }
  else if (b < 3072) { src = Wq;  dst = Wqkvb;             off = b - 2048; }
  else if (b < 3584) { src = Wkv; dst = Wqkvb + (1 << 20); off = b - 3072; }
  else               { src = Wp;  dst = Wpb;               off = b - 3584; }
  int i = off * 1024 + threadIdx.x * 4;
  float4 v = *(const float4*)(src + i);
  bf16x4 o;
  o[0] = (__bf16)v.x; o[1] = (__bf16)v.y; o[2] = (__bf16)v.z; o[3] = (__bf16)v.w;
  *(bf16x4*)(dst + i) = o;
}

// ---------------- GEMM core: 64x64 tile, BK=64, global_load_lds staging + LDS dbuf ----
// R1-proven form (127.6 us). R2's counted-vmcnt 3-buffer pipeline was null -> the
// GEMMs are not drain-bound; keep the simpler 2-buffer core.
// global_load_lds writes LDS linearly (wave base + lane*16B), so the XOR chunk
// swizzle moves to the GLOBAL source address (m173): LDS[row][c] = G[row][c^(row&7)].
// Waves stage 8-row groups: row&7 == l>>3, swizzled source chunk = (l&7)^(l>>3).
__device__ __forceinline__ void gemm_core64(const __bf16* __restrict__ A,
                                            const __bf16* __restrict__ B,
                                            int K,
                                            __bf16* AsB, __bf16* BsB,
                                            f32x4 (&acc)[4]) {
  const int tid = threadIdx.x;
  const int w = tid >> 6, l = tid & 63;
  const int quad = l >> 4, r16 = l & 15;
  const int srow = w * 16 + (l >> 3);
  const size_t soff = (size_t)srow * K + (size_t)(((l & 7) ^ (l >> 3)) * 8);
  const __bf16* gA = A + soff;
  const __bf16* gB = B + soff;
  __bf16* const lA = AsB + w * 1024;
  __bf16* const lB = BsB + w * 1024;
  const size_t rstep = (size_t)8 * K;
  int rA[2], rB[4][2];
#pragma unroll
  for (int ks = 0; ks < 2; ++ks) {
    int row = w * 16 + r16;
    rA[ks] = row * 64 + (((ks * 4 + quad) ^ (row & 7)) * 8);
  }
#pragma unroll
  for (int nt = 0; nt < 4; ++nt)
#pragma unroll
    for (int ks = 0; ks < 2; ++ks) {
      int row = nt * 16 + r16;
      rB[nt][ks] = row * 64 + (((ks * 4 + quad) ^ (row & 7)) * 8);
    }
  const int nIter = K >> 6;
  GLD16(gA, lA);
  GLD16(gA + rstep, lA + 512);
  GLD16(gB, lB);
  GLD16(gB + rstep, lB + 512);
  __syncthreads();
  int cur = 0;
  for (int it = 0; it < nIter; ++it) {
    if (it + 1 < nIter) {  // async-stage next K-slab into the other buffer
      const __bf16* ga = gA + ((it + 1) << 6);
      const __bf16* gb = gB + ((it + 1) << 6);
      __bf16* la = lA + ((cur ^ 1) << 12);
      __bf16* lb = lB + ((cur ^ 1) << 12);
      GLD16(ga, la);
      GLD16(ga + rstep, la + 512);
      GLD16(gb, lb);
      GLD16(gb + rstep, lb + 512);
    }
    const __bf16* Asc = AsB + (cur << 12);
    const __bf16* Bsc = BsB + (cur << 12);
#pragma unroll
    for (int ks = 0; ks < 2; ++ks) {
      bf16x8 fa  = *(const bf16x8*)(Asc + rA[ks]);
      bf16x8 fb0 = *(const bf16x8*)(Bsc + rB[0][ks]);
      bf16x8 fb1 = *(const bf16x8*)(Bsc + rB[1][ks]);
      bf16x8 fb2 = *(const bf16x8*)(Bsc + rB[2][ks]);
      bf16x8 fb3 = *(const bf16x8*)(Bsc + rB[3][ks]);
      acc[0] = MFMA16(fa, fb0, acc[0]);
      acc[1] = MFMA16(fa, fb1, acc[1]);
      acc[2] = MFMA16(fa, fb2, acc[2]);
      acc[3] = MFMA16(fa, fb3, acc[3]);
    }
    if (it + 1 < nIter) {
      __syncthreads();  // drains vmcnt(0): next slab resident; old buffer free
      cur ^= 1;
    }
  }
}

// ---------------- QKV GEMM + fused norm+RoPE (Q,K) / V-transpose epilogue ----------
__global__ __launch_bounds__(256) void gemm_qkv_kernel(const __bf16* __restrict__ xb,
                                                       const __bf16* __restrict__ Wqkvb,
                                                       const float2* __restrict__ ropeT,
                                                       __bf16* __restrict__ Qb,
                                                       __bf16* __restrict__ Kb,
                                                       __bf16* __restrict__ Vt) {
  __shared__ __align__(16) __bf16 smem[16384];  // As 2x4096 | Bs 2x4096 (32 KB)
  __bf16* AsB = smem;
  __bf16* BsB = smem + 8192;
  f32x4 acc[4] = {};
  const int m0 = blockIdx.y * 64, n0 = blockIdx.x * 64;
  gemm_core64(xb + (size_t)m0 * C_DIM, Wqkvb + (size_t)n0 * C_DIM, C_DIM, AsB, BsB, acc);
  const int tid = threadIdx.x;
  const int w = tid >> 6, l = tid & 63, quad = l >> 4, r16 = l & 15;
  if (n0 < 1280) {  // Q or K: L2-norm + RoPE
    const bool isQ = n0 < 1024;
    const int head = isQ ? (n0 >> 6) : ((n0 - 1024) >> 6);
    __bf16* dstBase = (isQ ? Qb : Kb) + (size_t)head * T_SEQ * HD;
    const float osc = isQ ? 0.125f : 1.0f;  // fold 1/sqrt(d) into Q (2^-3 exact)
#pragma unroll
    for (int r = 0; r < 4; ++r) {
      float ss = acc[0][r] * acc[0][r] + acc[1][r] * acc[1][r] +
                 acc[2][r] * acc[2][r] + acc[3][r] * acc[3][r];
#pragma unroll
      for (int m = 1; m < 16; m <<= 1) ss += __shfl_xor(ss, m, 64);
      const float inv = osc / (sqrtf(ss) + 1e-6f);
      const int t = m0 + w * 16 + quad * 4 + r;
      const float2 cs0 = ropeT[t * 32 + r16];
      const float2 cs1 = ropeT[t * 32 + 16 + r16];
      const float v0 = acc[0][r] * inv, v1 = acc[1][r] * inv;
      const float v2 = acc[2][r] * inv, v3 = acc[3][r] * inv;
      __bf16* dst = dstBase + (size_t)t * HD;
      dst[r16]      = (__bf16)(v0 * cs0.x - v2 * cs0.y);
      dst[16 + r16] = (__bf16)(v1 * cs1.x - v3 * cs1.y);
      dst[32 + r16] = (__bf16)(v2 * cs0.x + v0 * cs0.y);
      dst[48 + r16] = (__bf16)(v3 * cs1.x + v1 * cs1.y);
    }
  } else {  // V: transpose to Vt[kvh][d][t] via reused LDS
    const int kvh = (n0 - 1280) >> 6;
    __syncthreads();  // all waves done reading As/Bs
    __bf16* Vs = smem;  // [64 d][stride 136] = 17.4 KB <= 32 KB
#pragma unroll
    for (int nt = 0; nt < 4; ++nt)
#pragma unroll
      for (int r = 0; r < 4; ++r)
        Vs[(nt * 16 + r16) * 136 + w * 16 + quad * 4 + r] = (__bf16)acc[nt][r];
    __syncthreads();
    const int d = tid >> 2, tc = (tid & 3) * 16;
    __bf16* dst = Vt + ((size_t)kvh * HD + d) * T_SEQ + m0 + tc;
    bf16x8 v0 = *(const bf16x8*)(Vs + d * 136 + tc);
    bf16x8 v1 = *(const bf16x8*)(Vs + d * 136 + tc + 8);
    *(bf16x8*)dst = v0;
    *(bf16x8*)(dst + 8) = v1;
  }
}

// ---------------- proj GEMM: grid (16, 32), f32 epilogue ----------------
__global__ __launch_bounds__(256) void gemm_proj_kernel(const __bf16* __restrict__ Yb,
                                                        const __bf16* __restrict__ Wpb,
                                                        float* __restrict__ C) {
  __shared__ __align__(16) __bf16 smem[16384];
  __bf16* AsB = smem;
  __bf16* BsB = smem + 8192;
  f32x4 acc[4] = {};
  const int m0 = blockIdx.y * 64, n0 = blockIdx.x * 64;
  gemm_core64(Yb + (size_t)m0 * C_DIM, Wpb + (size_t)n0 * C_DIM, C_DIM, AsB, BsB, acc);
  const int tid = threadIdx.x;
  const int w = tid >> 6, l = tid & 63, quad = l >> 4, r16 = l & 15;
  const int mrow = m0 + w * 16 + quad * 4;
  const int ncol = n0 + r16;
#pragma unroll
  for (int r = 0; r < 4; ++r) {
    size_t rowoff = (size_t)(mrow + r) * C_DIM;
    C[rowoff + ncol]      = acc[0][r];
    C[rowoff + ncol + 16] = acc[1][r];
    C[rowoff + ncol + 32] = acc[2][r];
    C[rowoff + ncol + 48] = acc[3][r];
  }
}

// ---------------- MFMA sliding-window attention, block-cooperative LDS-staged ----------
// R12: R3 counters showed attn = 47us with MfmaUtil 3.2%, VALUBusy 12.6% -> ~80%
// stall on exposed global-load latency, with every wave re-fetching the same K/V.
// New structure: block = 64 queries (4 waves x 16 rows, NO half-split/combine);
// per 64-key chunk the block stages K (8KB) + V (8KB) ONCE into LDS via 16
// global_load_lds calls (each wave its own 16 rows), double-buffered: issue chunk
// t+1's async loads -> compute chunk t from LDS -> __syncthreads (drains vmcnt,
// same proven semantics as gemm_core64). Source-side XOR swizzle (m173) gives the
// gemm-proven conflict-balanced ds_read_b128 fragment pattern. Global traffic /4,
// load latency hidden under ~800cyc compute. Numerics: same loads/exp/f32 sums,
// only window summation order changes (values in [0.88,1.13], sum<=640 -> ulp-level).
__global__ __launch_bounds__(256) void attn_mfma_kernel(const __bf16* __restrict__ Qb,
                                                        const __bf16* __restrict__ Kb,
                                                        const __bf16* __restrict__ Vt,
                                                        __bf16* __restrict__ Yb) {
  __shared__ __align__(16) __bf16 KVs[2][8192];   // per buf: K[64][64] | V[64][64]
  __shared__ __align__(16) __bf16 Pl[4][16][72];
  const int h = blockIdx.y, kvh = h >> 2;
  const int t0 = blockIdx.x * 64;
  const int tid = threadIdx.x;
  const int w = tid >> 6, l = tid & 63;
  const int quad = l >> 4, r16 = l & 15;
  const int rr = l >> 3;          // 0..7: staging row within 8-row group
  const int cc = (l & 7) ^ rr;    // swizzled source chunk (row&7 == rr for our rows)
  // Q fragments: wave w owns query rows t0+16w .. t0+16w+15
  const __bf16* qptr = Qb + ((size_t)h * T_SEQ + t0 + w * 16 + r16) * HD + quad * 8;
  bf16x8 aq0 = *(const bf16x8*)(qptr);
  bf16x8 aq1 = *(const bf16x8*)(qptr + 32);
  const int keyStart = max(0, t0 - (WIN - 1)) & ~63;   // = t0-512 (t0>=512) else 0
  const int nch = ((t0 + 64) - keyStart) >> 6;         // <= 9, block-uniform
  const __bf16* kbase = Kb + (size_t)kvh * T_SEQ * HD;
  const __bf16* vbase = Vt + (size_t)kvh * HD * T_SEQ;
  const int tq = t0 + w * 16 + quad * 4;  // + r
  f32x4 oacc[4] = {};
  float lsum[4] = {0.f, 0.f, 0.f, 0.f};

  {  // prologue: stage chunk 0 into buf 0
    __bf16* kd = &KVs[0][w * 1024];
    __bf16* vd = &KVs[0][4096 + w * 1024];
    const __bf16* kg = kbase + (size_t)(keyStart + w * 16 + rr) * HD + cc * 8;
    const __bf16* vg = vbase + (size_t)(w * 16 + rr) * T_SEQ + keyStart + cc * 8;
    GLD16(kg, kd); GLD16(kg + 8 * HD, kd + 512);
    GLD16(vg, vd); GLD16(vg + 8 * T_SEQ, vd + 512);
  }
  __syncthreads();
  int buf = 0;
  for (int it = 0; it < nch; ++it) {
    const int key0 = keyStart + (it << 6);
    if (it + 1 < nch) {  // async-stage next chunk into the other buffer
      const int kn = key0 + 64;
      __bf16* kd = &KVs[buf ^ 1][w * 1024];
      __bf16* vd = &KVs[buf ^ 1][4096 + w * 1024];
      const __bf16* kg = kbase + (size_t)(kn + w * 16 + rr) * HD + cc * 8;
      const __bf16* vg = vbase + (size_t)(w * 16 + rr) * T_SEQ + kn + cc * 8;
      GLD16(kg, kd); GLD16(kg + 8 * HD, kd + 512);
      GLD16(vg, vd); GLD16(vg + 8 * T_SEQ, vd + 512);
    }
    const __bf16* Ksc = &KVs[buf][0];
    const __bf16* Vsc = &KVs[buf][4096];
    f32x4 s[4] = {};
#pragma unroll
    for (int nt = 0; nt < 4; ++nt) {
      const int row = nt * 16 + r16;
      bf16x8 bk0 = *(const bf16x8*)(Ksc + row * 64 + ((quad ^ (row & 7)) * 8));
      bf16x8 bk1 = *(const bf16x8*)(Ksc + row * 64 + (((4 + quad) ^ (row & 7)) * 8));
      s[nt] = MFMA16(aq0, bk0, s[nt]);
      s[nt] = MFMA16(aq1, bk1, s[nt]);
    }
#pragma unroll
    for (int nt = 0; nt < 4; ++nt) {
      const int key = key0 + nt * 16 + r16;
#pragma unroll
      for (int r = 0; r < 4; ++r) {
        bool valid = (key <= tq + r) && (key > tq + r - WIN);
        float p = valid ? __expf(s[nt][r]) : 0.0f;
        lsum[r] += p;
        Pl[w][quad * 4 + r][nt * 16 + r16] = (__bf16)p;
      }
    }
    bf16x8 ap0 = *(const bf16x8*)(&Pl[w][r16][quad * 8]);
    bf16x8 ap1 = *(const bf16x8*)(&Pl[w][r16][32 + quad * 8]);
#pragma unroll
    for (int nt = 0; nt < 4; ++nt) {
      const int d = nt * 16 + r16;
      bf16x8 bv0 = *(const bf16x8*)(Vsc + d * 64 + ((quad ^ (d & 7)) * 8));
      bf16x8 bv1 = *(const bf16x8*)(Vsc + d * 64 + (((4 + quad) ^ (d & 7)) * 8));
      oacc[nt] = MFMA16(ap0, bv0, oacc[nt]);
      oacc[nt] = MFMA16(ap1, bv1, oacc[nt]);
    }
    __syncthreads();  // drains vmcnt: next chunk resident; old buffer free
    buf ^= 1;
  }
#pragma unroll
  for (int r = 0; r < 4; ++r) {
#pragma unroll
    for (int m = 1; m < 16; m <<= 1) lsum[r] += __shfl_xor(lsum[r], m, 64);
  }
#pragma unroll
  for (int r = 0; r < 4; ++r) {
    const float inv = 1.0f / lsum[r];
    const size_t row = (size_t)(tq + r);
#pragma unroll
    for (int nt = 0; nt < 4; ++nt)
      Yb[row * C_DIM + h * HD + nt * 16 + r16] = (__bf16)(oacc[nt][r] * inv);
  }
}

extern "C" void kernel_launch(void* const* d_in, const int* in_sizes, int n_in,
                              void* d_out, int out_size, void* d_ws, size_t ws_size,
                              hipStream_t stream) {
  const float* x     = (const float*)d_in[0];
  const float* Wq    = (const float*)d_in[1];
  const float* Wkv   = (const float*)d_in[2];
  const float* Wproj = (const float*)d_in[3];
  float* out = (float*)d_out;

  __bf16* xb    = (__bf16*)d_ws;                         // [2048][1024]
  __bf16* Wqkvb = xb + (size_t)T_SEQ * C_DIM;            // [1536][1024]
  __bf16* Wpb   = Wqkvb + (size_t)1536 * C_DIM;          // [1024][1024]
  __bf16* Qb    = Wpb + (size_t)C_DIM * C_DIM;           // [16][2048][64]
  __bf16* Kb    = Qb + (size_t)NH * T_SEQ * HD;          // [4][2048][64]
  __bf16* Vt    = Kb + (size_t)NKV * T_SEQ * HD;         // [4][64][2048]
  __bf16* Yb    = Vt + (size_t)NKV * HD * T_SEQ;         // [2048][1024]
  float2* ropeT = (float2*)(Yb + (size_t)T_SEQ * C_DIM); // [2048][32]

  prep_kernel<<<4864, 256, 0, stream>>>(x, Wq, Wkv, Wproj, xb, Wqkvb, Wpb, ropeT);
  gemm_qkv_kernel<<<dim3(24, 32), 256, 0, stream>>>(xb, Wqkvb, ropeT, Qb, Kb, Vt);
  attn_mfma_kernel<<<dim3(T_SEQ / 64, NH), 256, 0, stream>>>(Qb, Kb, Vt, Yb);
  gemm_proj_kernel<<<dim3(16, 32), 256, 0, stream>>>(Yb, Wpb, out);
}